// Round 1
// baseline (2213.688 us; speedup 1.0000x reference)
//
#include <hip/hip_runtime.h>
#include <math.h>

#define NB 2
#define SS 2048
#define HH 1024
#define NHEAD 16
#define HDIM 64
#define NTOK (NB * SS)  // 4096

// ---------------------------------------------------------------------------
// GEMM: C[M][N] = A[M][K] @ W[K][N] + bias[N]   (all f32, row-major)
// 64x64 tile per block, 256 threads, 4x4 micro-tile per thread, BK=16.
// ---------------------------------------------------------------------------
__global__ __launch_bounds__(256) void gemm_bias_f32(
    const float* __restrict__ A, const float* __restrict__ W,
    const float* __restrict__ bias, float* __restrict__ C,
    int M, int N, int K)
{
    __shared__ float As[64][16];
    __shared__ float Bs[16][64];

    const int tid = threadIdx.x;
    const int tx = tid & 15;       // 0..15 col group
    const int ty = tid >> 4;       // 0..15 row group
    const int m0 = blockIdx.y * 64;
    const int n0 = blockIdx.x * 64;

    // loader mapping
    const int ar = tid >> 2;             // 0..63
    const int ac = (tid & 3) << 2;       // 0,4,8,12
    const int br = tid >> 4;             // 0..15
    const int bc = (tid & 15) << 2;      // 0..60

    float acc[4][4] = {{0.f}};

    for (int k0 = 0; k0 < K; k0 += 16) {
        float4 av = *reinterpret_cast<const float4*>(A + (size_t)(m0 + ar) * K + k0 + ac);
        float4 bv = *reinterpret_cast<const float4*>(W + (size_t)(k0 + br) * N + n0 + bc);
        *reinterpret_cast<float4*>(&As[ar][ac]) = av;
        *reinterpret_cast<float4*>(&Bs[br][bc]) = bv;
        __syncthreads();
#pragma unroll
        for (int kk = 0; kk < 16; ++kk) {
            float ra[4], rb[4];
#pragma unroll
            for (int i = 0; i < 4; ++i) ra[i] = As[ty * 4 + i][kk];
#pragma unroll
            for (int j = 0; j < 4; ++j) rb[j] = Bs[kk][tx * 4 + j];
#pragma unroll
            for (int i = 0; i < 4; ++i)
#pragma unroll
                for (int j = 0; j < 4; ++j)
                    acc[i][j] += ra[i] * rb[j];
        }
        __syncthreads();
    }

#pragma unroll
    for (int i = 0; i < 4; ++i) {
        const int m = m0 + ty * 4 + i;
        const int n = n0 + tx * 4;
        float4 o;
        o.x = acc[i][0] + bias[n + 0];
        o.y = acc[i][1] + bias[n + 1];
        o.z = acc[i][2] + bias[n + 2];
        o.w = acc[i][3] + bias[n + 3];
        *reinterpret_cast<float4*>(&C[(size_t)m * N + n]) = o;
    }
}

// ---------------------------------------------------------------------------
// Flash attention (f32): grid = (S/32, B*NH), block = 256.
// Each block: 32 q-rows of one (b,h). 8 lanes per q-row (r = tid>>3, cg = tid&7).
// K/V tiles of 64 rows staged in LDS (padded +1 -> conflict-free reads).
// Online softmax with running (m, l) per row, output acc in registers (8/thread).
// ---------------------------------------------------------------------------
__global__ __launch_bounds__(256) void attn_f32(
    const float* __restrict__ Qg, const float* __restrict__ Kg,
    const float* __restrict__ Vg, const float* __restrict__ maskg,
    float* __restrict__ ctx)
{
    __shared__ float Qs[32][HDIM + 1];
    __shared__ float Ks[64][HDIM + 1];
    __shared__ float Vs[64][HDIM + 1];
    __shared__ float Ps[32][65];
    __shared__ float Ms[64];

    const int tid = threadIdx.x;
    const int bh = blockIdx.y;
    const int b = bh / NHEAD;
    const int h = bh % NHEAD;
    const int q0 = blockIdx.x * 32;

    // ---- stage Q tile (32 x 64) ----
    {
        const int r = tid >> 3;            // 0..31
        const int c = (tid & 7) << 3;      // 0..56
        const float* src = Qg + ((size_t)(b * SS + q0 + r)) * HH + h * HDIM + c;
        float4 v0 = *reinterpret_cast<const float4*>(src);
        float4 v1 = *reinterpret_cast<const float4*>(src + 4);
        Qs[r][c + 0] = v0.x; Qs[r][c + 1] = v0.y; Qs[r][c + 2] = v0.z; Qs[r][c + 3] = v0.w;
        Qs[r][c + 4] = v1.x; Qs[r][c + 5] = v1.y; Qs[r][c + 6] = v1.z; Qs[r][c + 7] = v1.w;
    }

    const int r  = tid >> 3;   // q-row within tile (0..31)
    const int cg = tid & 7;    // column-group / dim-group lane (0..7)

    float m_run = -1e30f;
    float l_run = 0.f;
    float o[8];
#pragma unroll
    for (int j = 0; j < 8; ++j) o[j] = 0.f;

    const int r2 = tid >> 2;            // 0..63  (K/V stage row)
    const int c2 = (tid & 3) << 4;      // 0,16,32,48

    for (int kt = 0; kt < SS / 64; ++kt) {
        __syncthreads();  // protect previous iter's LDS reads
        // ---- stage mask ----
        if (tid < 64) Ms[tid] = maskg[(size_t)b * SS + kt * 64 + tid] * -10000.f;
        // ---- stage K, V tiles (64 x 64 each) ----
        {
            const float* kp = Kg + ((size_t)(b * SS + kt * 64 + r2)) * HH + h * HDIM + c2;
            const float* vp = Vg + ((size_t)(b * SS + kt * 64 + r2)) * HH + h * HDIM + c2;
#pragma unroll
            for (int u = 0; u < 4; ++u) {
                float4 kv = *reinterpret_cast<const float4*>(kp + u * 4);
                float4 vv = *reinterpret_cast<const float4*>(vp + u * 4);
                Ks[r2][c2 + u * 4 + 0] = kv.x; Ks[r2][c2 + u * 4 + 1] = kv.y;
                Ks[r2][c2 + u * 4 + 2] = kv.z; Ks[r2][c2 + u * 4 + 3] = kv.w;
                Vs[r2][c2 + u * 4 + 0] = vv.x; Vs[r2][c2 + u * 4 + 1] = vv.y;
                Vs[r2][c2 + u * 4 + 2] = vv.z; Vs[r2][c2 + u * 4 + 3] = vv.w;
            }
        }
        __syncthreads();

        // ---- scores: s[j] = Q[r] . K[cg*8+j]  (j = 0..7) ----
        float sc[8];
#pragma unroll
        for (int j = 0; j < 8; ++j) sc[j] = 0.f;
        for (int d = 0; d < HDIM; ++d) {
            const float qv = Qs[r][d];
#pragma unroll
            for (int j = 0; j < 8; ++j) sc[j] += qv * Ks[cg * 8 + j][d];
        }
#pragma unroll
        for (int j = 0; j < 8; ++j) sc[j] = sc[j] * 0.125f + Ms[cg * 8 + j];

        // ---- online softmax ----
        float tmax = sc[0];
#pragma unroll
        for (int j = 1; j < 8; ++j) tmax = fmaxf(tmax, sc[j]);
#pragma unroll
        for (int mskw = 1; mskw < 8; mskw <<= 1)
            tmax = fmaxf(tmax, __shfl_xor(tmax, mskw, 64));

        const float m_new = fmaxf(m_run, tmax);
        float p[8];
        float tsum = 0.f;
#pragma unroll
        for (int j = 0; j < 8; ++j) { p[j] = __expf(sc[j] - m_new); tsum += p[j]; }
#pragma unroll
        for (int mskw = 1; mskw < 8; mskw <<= 1)
            tsum += __shfl_xor(tsum, mskw, 64);

        const float scale_old = __expf(m_run - m_new);
        l_run = l_run * scale_old + tsum;
        m_run = m_new;

        // share p across the 8-lane row group via LDS (same wave -> no barrier)
#pragma unroll
        for (int j = 0; j < 8; ++j) Ps[r][cg * 8 + j] = p[j];

#pragma unroll
        for (int j = 0; j < 8; ++j) o[j] *= scale_old;

        // ---- PV: o[d0+jj] += sum_c P[r][c] * V[c][d0+jj], d0 = cg*8 ----
        for (int c = 0; c < 64; ++c) {
            const float pv = Ps[r][c];
#pragma unroll
            for (int jj = 0; jj < 8; ++jj) o[jj] += pv * Vs[c][cg * 8 + jj];
        }
    }

    // ---- finalize & write ctx[token][h*64 + cg*8 + jj] ----
    const float inv_l = 1.0f / l_run;
    float* dst = ctx + ((size_t)(b * SS + q0 + r)) * HH + h * HDIM + cg * 8;
    float4 o0, o1;
    o0.x = o[0] * inv_l; o0.y = o[1] * inv_l; o0.z = o[2] * inv_l; o0.w = o[3] * inv_l;
    o1.x = o[4] * inv_l; o1.y = o[5] * inv_l; o1.z = o[6] * inv_l; o1.w = o[7] * inv_l;
    *reinterpret_cast<float4*>(dst + 0) = o0;
    *reinterpret_cast<float4*>(dst + 4) = o1;
}

// ---------------------------------------------------------------------------
extern "C" void kernel_launch(void* const* d_in, const int* in_sizes, int n_in,
                              void* d_out, int out_size, void* d_ws, size_t ws_size,
                              hipStream_t stream)
{
    const float* hs   = (const float*)d_in[0];
    const float* mask = (const float*)d_in[1];
    const float* Wq   = (const float*)d_in[2];
    const float* bq   = (const float*)d_in[3];
    const float* Wk   = (const float*)d_in[4];
    const float* bk   = (const float*)d_in[5];
    const float* Wv   = (const float*)d_in[6];
    const float* bv   = (const float*)d_in[7];
    const float* Wo   = (const float*)d_in[8];
    const float* bo   = (const float*)d_in[9];
    float* out = (float*)d_out;

    float* Q   = (float*)d_ws;
    float* Kw  = Q  + (size_t)NTOK * HH;
    float* Vw  = Kw + (size_t)NTOK * HH;
    float* ctx = Vw + (size_t)NTOK * HH;

    dim3 blk(256);
    dim3 gg(HH / 64, NTOK / 64);   // (16, 64)

    gemm_bias_f32<<<gg, blk, 0, stream>>>(hs, Wq, bq, Q,  NTOK, HH, HH);
    gemm_bias_f32<<<gg, blk, 0, stream>>>(hs, Wk, bk, Kw, NTOK, HH, HH);
    gemm_bias_f32<<<gg, blk, 0, stream>>>(hs, Wv, bv, Vw, NTOK, HH, HH);

    dim3 ga(SS / 32, NB * NHEAD);  // (64, 32)
    attn_f32<<<ga, blk, 0, stream>>>(Q, Kw, Vw, mask, ctx);

    gemm_bias_f32<<<gg, blk, 0, stream>>>(ctx, Wo, bo, out, NTOK, HH, HH);
}

// Round 2
// 633.789 us; speedup vs baseline: 3.4928x; 3.4928x over previous
//
#include <hip/hip_runtime.h>
#include <math.h>

#define NB 2
#define SS 2048
#define HH 1024
#define NHEAD 16
#define HDIM 64
#define NTOK (NB * SS)  // 4096

typedef __attribute__((ext_vector_type(8))) short short8;
typedef __attribute__((ext_vector_type(4))) float f32x4;

// byte-offset swizzle within a 128B LDS row: XOR chunk index with (row&7)
#define SWZ16(row, boff) ((boff) ^ (((row) & 7) << 4))

// f32 -> bf16 round-to-nearest-even
__device__ __forceinline__ unsigned short f2b(float x) {
    union { float f; unsigned int u; } v; v.f = x;
    unsigned int u = v.u + 0x7fff + ((v.u >> 16) & 1);
    return (unsigned short)(u >> 16);
}

// ---------------------------------------------------------------------------
// GEMM: C[M][N] = A[M][K] @ W[K][N] + bias[N]   (all f32, row-major)
// ---------------------------------------------------------------------------
__global__ __launch_bounds__(256) void gemm_bias_f32(
    const float* __restrict__ A, const float* __restrict__ W,
    const float* __restrict__ bias, float* __restrict__ C,
    int M, int N, int K)
{
    __shared__ float As[64][16];
    __shared__ float Bs[16][64];

    const int tid = threadIdx.x;
    const int tx = tid & 15;
    const int ty = tid >> 4;
    const int m0 = blockIdx.y * 64;
    const int n0 = blockIdx.x * 64;

    const int ar = tid >> 2;
    const int ac = (tid & 3) << 2;
    const int br = tid >> 4;
    const int bc = (tid & 15) << 2;

    float acc[4][4] = {{0.f}};

    for (int k0 = 0; k0 < K; k0 += 16) {
        float4 av = *reinterpret_cast<const float4*>(A + (size_t)(m0 + ar) * K + k0 + ac);
        float4 bv = *reinterpret_cast<const float4*>(W + (size_t)(k0 + br) * N + n0 + bc);
        *reinterpret_cast<float4*>(&As[ar][ac]) = av;
        *reinterpret_cast<float4*>(&Bs[br][bc]) = bv;
        __syncthreads();
#pragma unroll
        for (int kk = 0; kk < 16; ++kk) {
            float ra[4], rb[4];
#pragma unroll
            for (int i = 0; i < 4; ++i) ra[i] = As[ty * 4 + i][kk];
#pragma unroll
            for (int j = 0; j < 4; ++j) rb[j] = Bs[kk][tx * 4 + j];
#pragma unroll
            for (int i = 0; i < 4; ++i)
#pragma unroll
                for (int j = 0; j < 4; ++j)
                    acc[i][j] += ra[i] * rb[j];
        }
        __syncthreads();
    }

#pragma unroll
    for (int i = 0; i < 4; ++i) {
        const int m = m0 + ty * 4 + i;
        const int n = n0 + tx * 4;
        float4 o;
        o.x = acc[i][0] + bias[n + 0];
        o.y = acc[i][1] + bias[n + 1];
        o.z = acc[i][2] + bias[n + 2];
        o.w = acc[i][3] + bias[n + 3];
        *reinterpret_cast<float4*>(&C[(size_t)m * N + n]) = o;
    }
}

// ---------------------------------------------------------------------------
// Pack: Q,K f32 [NTOK][HH] -> bf16 head-major [bh][s][64];
//       V  f32 [NTOK][HH] -> bf16 transposed  [bh][64][s]
// ---------------------------------------------------------------------------
__global__ __launch_bounds__(256) void pack_qkv(
    const float* __restrict__ Qf, const float* __restrict__ Kf,
    const float* __restrict__ Vf,
    unsigned short* __restrict__ Qb, unsigned short* __restrict__ Kb,
    unsigned short* __restrict__ Vtb)
{
    const int gid = blockIdx.x * 256 + threadIdx.x;  // 0..524287

    // --- Q/K: coalesced read, head-major 16B-chunk write ---
    {
        const int s  = gid >> 7;
        const int cc = gid & 127;
        const int h  = cc >> 3;
        const int d0 = (cc & 7) * 8;
        const int b  = s >> 11, si = s & 2047;
        const size_t src = (size_t)s * HH + h * 64 + d0;
        const size_t dst = ((size_t)(b * 16 + h) * SS + si) * 64 + d0;
        short8 q8, k8;
#pragma unroll
        for (int j = 0; j < 8; ++j) {
            q8[j] = (short)f2b(Qf[src + j]);
            k8[j] = (short)f2b(Kf[src + j]);
        }
        *(short8*)(Qb + dst) = q8;
        *(short8*)(Kb + dst) = k8;
    }

    // --- V transpose: strided read, coalesced write along s ---
    {
        const int b  = gid >> 18;
        const int c2 = (gid >> 11) & 127;
        const int si = gid & 2047;
        const int h  = c2 >> 3;
        const int d0 = (c2 & 7) * 8;
        const size_t src = ((size_t)(b * 2048 + si)) * HH + h * 64 + d0;
#pragma unroll
        for (int j = 0; j < 8; ++j)
            Vtb[((size_t)((b * 16 + h) * 64) + d0 + j) * SS + si] = f2b(Vf[src + j]);
    }
}

// ---------------------------------------------------------------------------
// Flash attention, bf16 MFMA 16x16x32.
// grid = (S/64, B*NH), block = 256 (4 waves, each owns 16 q-rows).
// LDS: K tile [64 sk][64 d], Vt tile [64 d][64 sk] (both XOR-swizzled),
//      per-wave P tile [16 q][64 sk] (swizzled).
// ---------------------------------------------------------------------------
__global__ __launch_bounds__(256) void attn_mfma(
    const unsigned short* __restrict__ Qb, const unsigned short* __restrict__ Kb,
    const unsigned short* __restrict__ Vtb, const float* __restrict__ maskf,
    float* __restrict__ ctx)
{
    __shared__ __align__(16) unsigned short Ks[64 * 64];
    __shared__ __align__(16) unsigned short Vts[64 * 64];
    __shared__ __align__(16) unsigned short Ps[4][16 * 64];

    const int tid = threadIdx.x;
    const int l   = tid & 63;
    const int wq  = tid >> 6;       // wave id 0..3
    const int g   = l >> 4;         // lane group 0..3
    const int c   = l & 15;         // lane col 0..15
    const int bh  = blockIdx.y;
    const int b   = bh >> 4;
    const int h   = bh & 15;
    const int qw  = blockIdx.x * 64 + wq * 16;   // wave's q base (seq pos)

    const unsigned short* Qp = Qb  + (size_t)bh * SS * 64;
    const unsigned short* Kp = Kb  + (size_t)bh * SS * 64;
    const unsigned short* Vp = Vtb + (size_t)bh * 64 * SS;

    // hoisted Q A-fragments (row = qw + c, k-halves 0/1)
    short8 aq[2];
    {
        const unsigned short* qrow = Qp + (size_t)(qw + c) * 64;
        aq[0] = *(const short8*)(qrow + g * 8);
        aq[1] = *(const short8*)(qrow + 32 + g * 8);
    }

    float m_run[4], l_run[4];
    f32x4 o[4];
#pragma unroll
    for (int r = 0; r < 4; ++r) { m_run[r] = -1e30f; l_run[r] = 0.f; }
#pragma unroll
    for (int dt = 0; dt < 4; ++dt) o[dt] = (f32x4){0.f, 0.f, 0.f, 0.f};

    // staging: 512 16B-chunks per tile, 256 threads -> 2 chunks each per tile
    const int r0 = tid >> 3;        // rows 0..31 (and +32 for second chunk)
    const int c0 = tid & 7;         // chunk col 0..7

    for (int kt = 0; kt < 32; ++kt) {
        // ---- global loads (linear) ----
        const unsigned short* Kt = Kp + (size_t)(kt * 64) * 64;
        short8 kv0 = *(const short8*)(Kt + (size_t)r0 * 64 + c0 * 8);
        short8 kv1 = *(const short8*)(Kt + (size_t)(r0 + 32) * 64 + c0 * 8);
        short8 vv0 = *(const short8*)(Vp + (size_t)r0 * SS + kt * 64 + c0 * 8);
        short8 vv1 = *(const short8*)(Vp + (size_t)(r0 + 32) * SS + kt * 64 + c0 * 8);
        float mv[4];
#pragma unroll
        for (int t = 0; t < 4; ++t)
            mv[t] = maskf[b * SS + kt * 64 + t * 16 + c] * -10000.f;

        __syncthreads();   // previous tile's reads complete before overwrite
        *(short8*)((char*)Ks  + r0 * 128        + SWZ16(r0, c0 * 16)) = kv0;
        *(short8*)((char*)Ks  + (r0 + 32) * 128 + SWZ16(r0, c0 * 16)) = kv1;
        *(short8*)((char*)Vts + r0 * 128        + SWZ16(r0, c0 * 16)) = vv0;
        *(short8*)((char*)Vts + (r0 + 32) * 128 + SWZ16(r0, c0 * 16)) = vv1;
        __syncthreads();

        // ---- QK^T: S[q][sk], 4 sk-tiles x 2 k-halves ----
        f32x4 s4[4];
#pragma unroll
        for (int t = 0; t < 4; ++t) s4[t] = (f32x4){0.f, 0.f, 0.f, 0.f};
#pragma unroll
        for (int ks = 0; ks < 2; ++ks) {
#pragma unroll
            for (int t = 0; t < 4; ++t) {
                const int row = t * 16 + c;
                short8 kf = *(const short8*)((char*)Ks + row * 128 +
                                             SWZ16(row, ks * 64 + g * 16));
                s4[t] = __builtin_amdgcn_mfma_f32_16x16x32_bf16(aq[ks], kf, s4[t], 0, 0, 0);
            }
        }

        // ---- scale + mask ----
#pragma unroll
        for (int t = 0; t < 4; ++t)
#pragma unroll
            for (int r = 0; r < 4; ++r)
                s4[t][r] = s4[t][r] * 0.125f + mv[t];

        // ---- online softmax (rows live in reg index; cols across 16 lanes) ----
        float mx[4];
#pragma unroll
        for (int r = 0; r < 4; ++r) {
            mx[r] = fmaxf(fmaxf(s4[0][r], s4[1][r]), fmaxf(s4[2][r], s4[3][r]));
        }
#pragma unroll
        for (int off = 1; off < 16; off <<= 1)
#pragma unroll
            for (int r = 0; r < 4; ++r)
                mx[r] = fmaxf(mx[r], __shfl_xor(mx[r], off, 64));

        float scale[4];
#pragma unroll
        for (int r = 0; r < 4; ++r) {
            const float mn = fmaxf(m_run[r], mx[r]);
            scale[r] = __expf(m_run[r] - mn);
            m_run[r] = mn;
        }

        float rsum[4] = {0.f, 0.f, 0.f, 0.f};
        unsigned short pb[4][4];
#pragma unroll
        for (int t = 0; t < 4; ++t)
#pragma unroll
            for (int r = 0; r < 4; ++r) {
                const float p = __expf(s4[t][r] - m_run[r]);
                rsum[r] += p;
                pb[t][r] = f2b(p);
            }
#pragma unroll
        for (int off = 1; off < 16; off <<= 1)
#pragma unroll
            for (int r = 0; r < 4; ++r)
                rsum[r] += __shfl_xor(rsum[r], off, 64);

#pragma unroll
        for (int r = 0; r < 4; ++r)
            l_run[r] = l_run[r] * scale[r] + rsum[r];
#pragma unroll
        for (int dt = 0; dt < 4; ++dt)
#pragma unroll
            for (int r = 0; r < 4; ++r)
                o[dt][r] *= scale[r];

        // ---- P (D-layout) -> LDS (A-layout source), per-wave, no barrier ----
#pragma unroll
        for (int t = 0; t < 4; ++t)
#pragma unroll
            for (int r = 0; r < 4; ++r) {
                const int row = 4 * g + r;
                *(unsigned short*)((char*)Ps[wq] + row * 128 +
                                   SWZ16(row, (t * 16 + c) * 2)) = pb[t][r];
            }

        // ---- PV: ctx[q][d] += P[q][sk] * V[sk][d] ----
#pragma unroll
        for (int ks = 0; ks < 2; ++ks) {
            short8 ap = *(const short8*)((char*)Ps[wq] + c * 128 +
                                         SWZ16(c, ks * 64 + g * 16));
#pragma unroll
            for (int dt = 0; dt < 4; ++dt) {
                const int vrow = dt * 16 + c;
                short8 bv = *(const short8*)((char*)Vts + vrow * 128 +
                                             SWZ16(vrow, ks * 64 + g * 16));
                o[dt] = __builtin_amdgcn_mfma_f32_16x16x32_bf16(ap, bv, o[dt], 0, 0, 0);
            }
        }
    }

    // ---- finalize: ctx[b*S + q][h*64 + d] ----
#pragma unroll
    for (int r = 0; r < 4; ++r) {
        const float inv_l = 1.0f / l_run[r];
        const int q = qw + 4 * g + r;
#pragma unroll
        for (int dt = 0; dt < 4; ++dt)
            ctx[((size_t)(b * SS + q)) * HH + h * 64 + dt * 16 + c] = o[dt][r] * inv_l;
    }
}

// ---------------------------------------------------------------------------
extern "C" void kernel_launch(void* const* d_in, const int* in_sizes, int n_in,
                              void* d_out, int out_size, void* d_ws, size_t ws_size,
                              hipStream_t stream)
{
    const float* hs   = (const float*)d_in[0];
    const float* mask = (const float*)d_in[1];
    const float* Wq   = (const float*)d_in[2];
    const float* bq   = (const float*)d_in[3];
    const float* Wk   = (const float*)d_in[4];
    const float* bk   = (const float*)d_in[5];
    const float* Wv   = (const float*)d_in[6];
    const float* bv   = (const float*)d_in[7];
    const float* Wo   = (const float*)d_in[8];
    const float* bo   = (const float*)d_in[9];
    float* out = (float*)d_out;

    float* Q   = (float*)d_ws;
    float* Kw  = Q  + (size_t)NTOK * HH;
    float* Vw  = Kw + (size_t)NTOK * HH;
    float* ctx = Vw + (size_t)NTOK * HH;
    unsigned short* Qb  = (unsigned short*)(ctx + (size_t)NTOK * HH);
    unsigned short* Kb  = Qb + (size_t)NTOK * HDIM * NHEAD;   // == NTOK*HH elems
    unsigned short* Vtb = Kb + (size_t)NTOK * HDIM * NHEAD;

    dim3 blk(256);
    dim3 gg(HH / 64, NTOK / 64);   // (16, 64)

    gemm_bias_f32<<<gg, blk, 0, stream>>>(hs, Wq, bq, Q,  NTOK, HH, HH);
    gemm_bias_f32<<<gg, blk, 0, stream>>>(hs, Wk, bk, Kw, NTOK, HH, HH);
    gemm_bias_f32<<<gg, blk, 0, stream>>>(hs, Wv, bv, Vw, NTOK, HH, HH);

    pack_qkv<<<dim3(2048), blk, 0, stream>>>(Q, Kw, Vw, Qb, Kb, Vtb);

    dim3 ga(SS / 64, NB * NHEAD);  // (32, 32)
    attn_mfma<<<ga, blk, 0, stream>>>(Qb, Kb, Vtb, mask, ctx);

    gemm_bias_f32<<<gg, blk, 0, stream>>>(ctx, Wo, bo, out, NTOK, HH, HH);
}

// Round 3
// 218.614 us; speedup vs baseline: 10.1260x; 2.8991x over previous
//
#include <hip/hip_runtime.h>
#include <math.h>

#define NB 2
#define SS 2048
#define HH 1024
#define NHEAD 16
#define HDIM 64
#define NTOK (NB * SS)  // 4096

typedef __attribute__((ext_vector_type(8))) short short8;
typedef __attribute__((ext_vector_type(4))) float f32x4;

// byte-offset swizzle within a 128B LDS row: XOR 16B-chunk index with (row&7)
#define SWZ16(row, boff) ((boff) ^ (((row) & 7) << 4))

// f32 -> bf16 round-to-nearest-even
__device__ __forceinline__ unsigned short f2b(float x) {
    union { float f; unsigned int u; } v; v.f = x;
    unsigned int u = v.u + 0x7fff + ((v.u >> 16) & 1);
    return (unsigned short)(u >> 16);
}

// async global->LDS, 16B per lane; LDS dest is wave-uniform base + lane*16
__device__ __forceinline__ void gl16(const void* g, void* l) {
    __builtin_amdgcn_global_load_lds(
        (const __attribute__((address_space(1))) void*)g,
        (__attribute__((address_space(3))) void*)l, 16, 0, 0);
}

// ---------------------------------------------------------------------------
// hs f32 -> bf16 row-major
// ---------------------------------------------------------------------------
__global__ __launch_bounds__(256) void cvt_hs(
    const float* __restrict__ X, unsigned short* __restrict__ Y)
{
    const size_t i = ((size_t)blockIdx.x * 256 + threadIdx.x) * 8;
    float4 v0 = *(const float4*)(X + i);
    float4 v1 = *(const float4*)(X + i + 4);
    short8 o;
    o[0] = f2b(v0.x); o[1] = f2b(v0.y); o[2] = f2b(v0.z); o[3] = f2b(v0.w);
    o[4] = f2b(v1.x); o[5] = f2b(v1.y); o[6] = f2b(v1.z); o[7] = f2b(v1.w);
    *(short8*)(Y + i) = o;
}

// ---------------------------------------------------------------------------
// W f32 [K][N] -> Wt bf16 [N][K]  (4 weights via blockIdx.z), 64x64 LDS tiles
// ---------------------------------------------------------------------------
__global__ __launch_bounds__(256) void transpose_w(
    const float* __restrict__ W0, const float* __restrict__ W1,
    const float* __restrict__ W2, const float* __restrict__ W3,
    unsigned short* __restrict__ Wt)
{
    const float* W = blockIdx.z == 0 ? W0 : blockIdx.z == 1 ? W1 :
                     blockIdx.z == 2 ? W2 : W3;
    unsigned short* dst = Wt + (size_t)blockIdx.z * HH * HH;
    __shared__ unsigned short T[64][72];   // 144B pitch, 16B aligned
    const int tid = threadIdx.x;
    const int n0 = blockIdx.x * 64, k0 = blockIdx.y * 64;
    {
        const int r = tid >> 2, c4 = (tid & 3) * 16;
        const float* src = W + (size_t)(k0 + r) * HH + n0 + c4;
#pragma unroll
        for (int j = 0; j < 16; j += 4) {
            float4 v = *(const float4*)(src + j);
            T[c4 + j + 0][r] = f2b(v.x); T[c4 + j + 1][r] = f2b(v.y);
            T[c4 + j + 2][r] = f2b(v.z); T[c4 + j + 3][r] = f2b(v.w);
        }
    }
    __syncthreads();
    {
        const int n = tid >> 2, sc = (tid & 3) * 2;
#pragma unroll
        for (int u = 0; u < 2; ++u) {
            short8 v = *(const short8*)&T[n][(sc + u) * 8];
            *(short8*)(dst + (size_t)(n0 + n) * HH + k0 + (sc + u) * 8) = v;
        }
    }
}

// ---------------------------------------------------------------------------
// bf16 MFMA GEMM: C[M=4096][N=1024] = A[M][K=1024] @ Wt[N][K]^T + bias
// BM=BN=128, BK=64, 4 waves (64x64 each), LDS double-buffered,
// global_load_lds staging with inverse-swizzled source (rule #21).
// OUT=0: bf16 head-major [(b*16+h)][si][d];  OUT=2: f32 row-major.
// ---------------------------------------------------------------------------
template<int OUT>
__global__ __launch_bounds__(256) void gemm_bf16(
    const unsigned short* __restrict__ A, const unsigned short* __restrict__ Bt,
    const float* __restrict__ bias, void* __restrict__ Cout)
{
    __shared__ __align__(16) unsigned short As[2][128 * 64];
    __shared__ __align__(16) unsigned short Bs[2][128 * 64];

    const int tid = threadIdx.x;
    const int w  = tid >> 6;
    const int l  = tid & 63;
    const int g  = l >> 4, c = l & 15;
    const int wr = w >> 1, wc = w & 1;
    const int m0 = blockIdx.y * 128, n0 = blockIdx.x * 128;

    // staging source mapping: lane covers physical (row = base + l/8, chunk = l%8);
    // global chunk = (l%8) ^ (row&7) so that swizzled reads recover logical data
    const int dr = l >> 3;
    const int gc = (l & 7) ^ dr;

    const unsigned short* aBase = A  + (size_t)(m0 + w * 32 + dr) * HH + gc * 8;
    const unsigned short* bBase = Bt + (size_t)(n0 + w * 32 + dr) * HH + gc * 8;

    f32x4 acc[4][4];
#pragma unroll
    for (int mi = 0; mi < 4; ++mi)
#pragma unroll
        for (int ni = 0; ni < 4; ++ni)
            acc[mi][ni] = (f32x4){0.f, 0.f, 0.f, 0.f};

    const int swz = (c & 7) * 8;   // element-XOR within 64-elem row

#define STAGE(kt_, bb) {                                                      \
    const int koff = (kt_) * 64;                                              \
    _Pragma("unroll")                                                         \
    for (int i_ = 0; i_ < 4; ++i_) {                                          \
        gl16(aBase + koff + (size_t)i_ * 8 * HH, (void*)&As[bb][(w*4+i_)*512]); \
        gl16(bBase + koff + (size_t)i_ * 8 * HH, (void*)&Bs[bb][(w*4+i_)*512]); \
    } }

    STAGE(0, 0);
    __syncthreads();
    int cur = 0;

    for (int kt = 0; kt < 16; ++kt) {
        if (kt < 15) STAGE(kt + 1, cur ^ 1);

        short8 af[2][4], bf[2][4];
#pragma unroll
        for (int ks = 0; ks < 2; ++ks) {
            const int kb = ks * 32;
#pragma unroll
            for (int mi = 0; mi < 4; ++mi) {
                const int row = wr * 64 + mi * 16 + c;
                af[ks][mi] = *(const short8*)&As[cur][row * 64 + ((kb + g * 8) ^ swz)];
            }
#pragma unroll
            for (int ni = 0; ni < 4; ++ni) {
                const int row = wc * 64 + ni * 16 + c;
                bf[ks][ni] = *(const short8*)&Bs[cur][row * 64 + ((kb + g * 8) ^ swz)];
            }
        }
#pragma unroll
        for (int ks = 0; ks < 2; ++ks)
#pragma unroll
            for (int mi = 0; mi < 4; ++mi)
#pragma unroll
                for (int ni = 0; ni < 4; ++ni)
                    acc[mi][ni] = __builtin_amdgcn_mfma_f32_16x16x32_bf16(
                        af[ks][mi], bf[ks][ni], acc[mi][ni], 0, 0, 0);

        __syncthreads();
        cur ^= 1;
    }
#undef STAGE

    // epilogue: D-layout element (mi,ni,j): m = .. + g*4 + j, n = .. + c
#pragma unroll
    for (int ni = 0; ni < 4; ++ni) {
        const int n = n0 + wc * 64 + ni * 16 + c;
        const float bv = bias[n];
#pragma unroll
        for (int mi = 0; mi < 4; ++mi) {
            const int mBase = m0 + wr * 64 + mi * 16 + g * 4;
#pragma unroll
            for (int j = 0; j < 4; ++j) {
                const int m = mBase + j;
                const float val = acc[mi][ni][j] + bv;
                if (OUT == 0) {
                    const int b = m >> 11, si = m & 2047;
                    const int h = n >> 6,  d = n & 63;
                    ((unsigned short*)Cout)[(((size_t)(b * 16 + h)) * SS + si) * 64 + d] = f2b(val);
                } else {
                    ((float*)Cout)[(size_t)m * HH + n] = val;
                }
            }
        }
    }
}

// ---------------------------------------------------------------------------
// V head-major [bh][s][64] -> Vt [bh][64][s], 64x64 LDS tiles
// ---------------------------------------------------------------------------
__global__ __launch_bounds__(256) void vtrans(
    const unsigned short* __restrict__ Vh, unsigned short* __restrict__ Vt)
{
    __shared__ unsigned short T[64][72];
    const int tid = threadIdx.x;
    const int bh = blockIdx.y;
    const int s0 = blockIdx.x * 64;
    {
        const int r = tid >> 2, dc = (tid & 3) * 16;
        const unsigned short* src = Vh + ((size_t)bh * SS + s0 + r) * 64 + dc;
        short8 v0 = *(const short8*)src;
        short8 v1 = *(const short8*)(src + 8);
#pragma unroll
        for (int j = 0; j < 8; ++j) {
            T[dc + j][r]     = (unsigned short)v0[j];
            T[dc + 8 + j][r] = (unsigned short)v1[j];
        }
    }
    __syncthreads();
    {
        const int d = tid >> 2, sc = (tid & 3) * 2;
#pragma unroll
        for (int u = 0; u < 2; ++u) {
            short8 v = *(const short8*)&T[d][(sc + u) * 8];
            *(short8*)(Vt + ((size_t)bh * 64 + d) * SS + s0 + (sc + u) * 8) = v;
        }
    }
}

// ---------------------------------------------------------------------------
// Flash attention, bf16 MFMA 16x16x32 (unchanged structure; bf16 ctx out)
// ---------------------------------------------------------------------------
__global__ __launch_bounds__(256) void attn_mfma(
    const unsigned short* __restrict__ Qb, const unsigned short* __restrict__ Kb,
    const unsigned short* __restrict__ Vtb, const float* __restrict__ maskf,
    unsigned short* __restrict__ ctx)
{
    __shared__ __align__(16) unsigned short Ks[64 * 64];
    __shared__ __align__(16) unsigned short Vts[64 * 64];
    __shared__ __align__(16) unsigned short Ps[4][16 * 64];

    const int tid = threadIdx.x;
    const int l   = tid & 63;
    const int wq  = tid >> 6;
    const int g   = l >> 4;
    const int c   = l & 15;
    const int bh  = blockIdx.y;
    const int b   = bh >> 4;
    const int h   = bh & 15;
    const int qw  = blockIdx.x * 64 + wq * 16;

    const unsigned short* Qp = Qb  + (size_t)bh * SS * 64;
    const unsigned short* Kp = Kb  + (size_t)bh * SS * 64;
    const unsigned short* Vp = Vtb + (size_t)bh * 64 * SS;

    short8 aq[2];
    {
        const unsigned short* qrow = Qp + (size_t)(qw + c) * 64;
        aq[0] = *(const short8*)(qrow + g * 8);
        aq[1] = *(const short8*)(qrow + 32 + g * 8);
    }

    float m_run[4], l_run[4];
    f32x4 o[4];
#pragma unroll
    for (int r = 0; r < 4; ++r) { m_run[r] = -1e30f; l_run[r] = 0.f; }
#pragma unroll
    for (int dt = 0; dt < 4; ++dt) o[dt] = (f32x4){0.f, 0.f, 0.f, 0.f};

    const int r0 = tid >> 3;
    const int c0 = tid & 7;

    for (int kt = 0; kt < 32; ++kt) {
        const unsigned short* Kt = Kp + (size_t)(kt * 64) * 64;
        short8 kv0 = *(const short8*)(Kt + (size_t)r0 * 64 + c0 * 8);
        short8 kv1 = *(const short8*)(Kt + (size_t)(r0 + 32) * 64 + c0 * 8);
        short8 vv0 = *(const short8*)(Vp + (size_t)r0 * SS + kt * 64 + c0 * 8);
        short8 vv1 = *(const short8*)(Vp + (size_t)(r0 + 32) * SS + kt * 64 + c0 * 8);
        float mv[4];
#pragma unroll
        for (int t = 0; t < 4; ++t)
            mv[t] = maskf[b * SS + kt * 64 + t * 16 + c] * -10000.f;

        __syncthreads();
        *(short8*)((char*)Ks  + r0 * 128        + SWZ16(r0, c0 * 16)) = kv0;
        *(short8*)((char*)Ks  + (r0 + 32) * 128 + SWZ16(r0, c0 * 16)) = kv1;
        *(short8*)((char*)Vts + r0 * 128        + SWZ16(r0, c0 * 16)) = vv0;
        *(short8*)((char*)Vts + (r0 + 32) * 128 + SWZ16(r0, c0 * 16)) = vv1;
        __syncthreads();

        f32x4 s4[4];
#pragma unroll
        for (int t = 0; t < 4; ++t) s4[t] = (f32x4){0.f, 0.f, 0.f, 0.f};
#pragma unroll
        for (int ks = 0; ks < 2; ++ks) {
#pragma unroll
            for (int t = 0; t < 4; ++t) {
                const int row = t * 16 + c;
                short8 kf = *(const short8*)((char*)Ks + row * 128 +
                                             SWZ16(row, ks * 64 + g * 16));
                s4[t] = __builtin_amdgcn_mfma_f32_16x16x32_bf16(aq[ks], kf, s4[t], 0, 0, 0);
            }
        }

#pragma unroll
        for (int t = 0; t < 4; ++t)
#pragma unroll
            for (int r = 0; r < 4; ++r)
                s4[t][r] = s4[t][r] * 0.125f + mv[t];

        float mx[4];
#pragma unroll
        for (int r = 0; r < 4; ++r)
            mx[r] = fmaxf(fmaxf(s4[0][r], s4[1][r]), fmaxf(s4[2][r], s4[3][r]));
#pragma unroll
        for (int off = 1; off < 16; off <<= 1)
#pragma unroll
            for (int r = 0; r < 4; ++r)
                mx[r] = fmaxf(mx[r], __shfl_xor(mx[r], off, 64));

        float scale[4];
#pragma unroll
        for (int r = 0; r < 4; ++r) {
            const float mn = fmaxf(m_run[r], mx[r]);
            scale[r] = __expf(m_run[r] - mn);
            m_run[r] = mn;
        }

        float rsum[4] = {0.f, 0.f, 0.f, 0.f};
        unsigned short pb[4][4];
#pragma unroll
        for (int t = 0; t < 4; ++t)
#pragma unroll
            for (int r = 0; r < 4; ++r) {
                const float p = __expf(s4[t][r] - m_run[r]);
                rsum[r] += p;
                pb[t][r] = f2b(p);
            }
#pragma unroll
        for (int off = 1; off < 16; off <<= 1)
#pragma unroll
            for (int r = 0; r < 4; ++r)
                rsum[r] += __shfl_xor(rsum[r], off, 64);

#pragma unroll
        for (int r = 0; r < 4; ++r)
            l_run[r] = l_run[r] * scale[r] + rsum[r];
#pragma unroll
        for (int dt = 0; dt < 4; ++dt)
#pragma unroll
            for (int r = 0; r < 4; ++r)
                o[dt][r] *= scale[r];

#pragma unroll
        for (int t = 0; t < 4; ++t)
#pragma unroll
            for (int r = 0; r < 4; ++r) {
                const int row = 4 * g + r;
                *(unsigned short*)((char*)Ps[wq] + row * 128 +
                                   SWZ16(row, (t * 16 + c) * 2)) = pb[t][r];
            }

#pragma unroll
        for (int ks = 0; ks < 2; ++ks) {
            short8 ap = *(const short8*)((char*)Ps[wq] + c * 128 +
                                         SWZ16(c, ks * 64 + g * 16));
#pragma unroll
            for (int dt = 0; dt < 4; ++dt) {
                const int vrow = dt * 16 + c;
                short8 bv = *(const short8*)((char*)Vts + vrow * 128 +
                                             SWZ16(vrow, ks * 64 + g * 16));
                o[dt] = __builtin_amdgcn_mfma_f32_16x16x32_bf16(ap, bv, o[dt], 0, 0, 0);
            }
        }
    }

#pragma unroll
    for (int r = 0; r < 4; ++r) {
        const float inv_l = 1.0f / l_run[r];
        const int q = qw + 4 * g + r;
#pragma unroll
        for (int dt = 0; dt < 4; ++dt)
            ctx[((size_t)(b * SS + q)) * HH + h * 64 + dt * 16 + c] =
                f2b(o[dt][r] * inv_l);
    }
}

// ---------------------------------------------------------------------------
extern "C" void kernel_launch(void* const* d_in, const int* in_sizes, int n_in,
                              void* d_out, int out_size, void* d_ws, size_t ws_size,
                              hipStream_t stream)
{
    const float* hs   = (const float*)d_in[0];
    const float* mask = (const float*)d_in[1];
    const float* Wq   = (const float*)d_in[2];
    const float* bq   = (const float*)d_in[3];
    const float* Wk   = (const float*)d_in[4];
    const float* bk   = (const float*)d_in[5];
    const float* Wv   = (const float*)d_in[6];
    const float* bv   = (const float*)d_in[7];
    const float* Wo   = (const float*)d_in[8];
    const float* bo   = (const float*)d_in[9];
    float* out = (float*)d_out;

    unsigned short* Ab   = (unsigned short*)d_ws;              // 4M shorts
    unsigned short* Wt   = Ab + (size_t)NTOK * HH;             // 4x1M shorts
    unsigned short* Qh   = Wt + (size_t)4 * HH * HH;
    unsigned short* Kh   = Qh + (size_t)NTOK * HH;
    unsigned short* Vh   = Kh + (size_t)NTOK * HH;
    unsigned short* Vt   = Vh + (size_t)NTOK * HH;
    unsigned short* ctxb = Vt + (size_t)NTOK * HH;

    dim3 blk(256);

    cvt_hs<<<dim3(NTOK * HH / (8 * 256)), blk, 0, stream>>>(hs, Ab);
    transpose_w<<<dim3(16, 16, 4), blk, 0, stream>>>(Wq, Wk, Wv, Wo, Wt);

    dim3 gg(HH / 128, NTOK / 128);   // (8, 32)
    gemm_bf16<0><<<gg, blk, 0, stream>>>(Ab, Wt + 0 * (size_t)HH * HH, bq, Qh);
    gemm_bf16<0><<<gg, blk, 0, stream>>>(Ab, Wt + 1 * (size_t)HH * HH, bk, Kh);
    gemm_bf16<0><<<gg, blk, 0, stream>>>(Ab, Wt + 2 * (size_t)HH * HH, bv, Vh);

    vtrans<<<dim3(SS / 64, NB * NHEAD), blk, 0, stream>>>(Vh, Vt);

    dim3 ga(SS / 64, NB * NHEAD);    // (32, 32)
    attn_mfma<<<ga, blk, 0, stream>>>(Qh, Kh, Vt, mask, ctxb);

    gemm_bf16<2><<<gg, blk, 0, stream>>>(ctxb, Wt + 3 * (size_t)HH * HH, bo, out);
}

// Round 4
// 154.490 us; speedup vs baseline: 14.3290x; 1.4151x over previous
//
#include <hip/hip_runtime.h>
#include <hip/hip_bf16.h>
#include <math.h>

#define NB 2
#define SS 2048
#define HH 1024
#define NHEAD 16
#define HDIM 64
#define NTOK (NB * SS)  // 4096

typedef __attribute__((ext_vector_type(8))) short short8;
typedef __attribute__((ext_vector_type(4))) float f32x4;
typedef __attribute__((ext_vector_type(16))) float f32x16;

// byte-offset swizzle within a 128B LDS row: XOR 16B-chunk index with (row&7)
#define SWZ16(row, boff) ((boff) ^ (((row) & 7) << 4))

// f32 -> bf16 round-to-nearest-even
__device__ __forceinline__ unsigned short f2b(float x) {
    union { float f; unsigned int u; } v; v.f = x;
    unsigned int u = v.u + 0x7fff + ((v.u >> 16) & 1);
    return (unsigned short)(u >> 16);
}

// pack two f32 -> one dword of 2 bf16 (lo = a, hi = b)
__device__ __forceinline__ unsigned pk2(float a, float b) {
    union { __hip_bfloat162 h; unsigned u; } cv;
    cv.h = __float22bfloat162_rn(make_float2(a, b));
    return cv.u;
}

// async global->LDS, 16B per lane
__device__ __forceinline__ void gl16(const void* g, void* l) {
    __builtin_amdgcn_global_load_lds(
        (const __attribute__((address_space(1))) void*)g,
        (__attribute__((address_space(3))) void*)l, 16, 0, 0);
}

// ---------------------------------------------------------------------------
// hs f32 -> bf16 row-major
// ---------------------------------------------------------------------------
__global__ __launch_bounds__(256) void cvt_hs(
    const float* __restrict__ X, unsigned short* __restrict__ Y)
{
    const size_t i = ((size_t)blockIdx.x * 256 + threadIdx.x) * 8;
    float4 v0 = *(const float4*)(X + i);
    float4 v1 = *(const float4*)(X + i + 4);
    short8 o;
    o[0] = f2b(v0.x); o[1] = f2b(v0.y); o[2] = f2b(v0.z); o[3] = f2b(v0.w);
    o[4] = f2b(v1.x); o[5] = f2b(v1.y); o[6] = f2b(v1.z); o[7] = f2b(v1.w);
    *(short8*)(Y + i) = o;
}

// ---------------------------------------------------------------------------
// W f32 [K][N] -> Wt bf16 [N][K]  (4 weights via blockIdx.z), 64x64 LDS tiles
// ---------------------------------------------------------------------------
__global__ __launch_bounds__(256) void transpose_w(
    const float* __restrict__ W0, const float* __restrict__ W1,
    const float* __restrict__ W2, const float* __restrict__ W3,
    unsigned short* __restrict__ Wt)
{
    const float* W = blockIdx.z == 0 ? W0 : blockIdx.z == 1 ? W1 :
                     blockIdx.z == 2 ? W2 : W3;
    unsigned short* dst = Wt + (size_t)blockIdx.z * HH * HH;
    __shared__ unsigned short T[64][72];
    const int tid = threadIdx.x;
    const int n0 = blockIdx.x * 64, k0 = blockIdx.y * 64;
    {
        const int r = tid >> 2, c4 = (tid & 3) * 16;
        const float* src = W + (size_t)(k0 + r) * HH + n0 + c4;
#pragma unroll
        for (int j = 0; j < 16; j += 4) {
            float4 v = *(const float4*)(src + j);
            T[c4 + j + 0][r] = f2b(v.x); T[c4 + j + 1][r] = f2b(v.y);
            T[c4 + j + 2][r] = f2b(v.z); T[c4 + j + 3][r] = f2b(v.w);
        }
    }
    __syncthreads();
    {
        const int n = tid >> 2, sc = (tid & 3) * 2;
#pragma unroll
        for (int u = 0; u < 2; ++u) {
            short8 v = *(const short8*)&T[n][(sc + u) * 8];
            *(short8*)(dst + (size_t)(n0 + n) * HH + k0 + (sc + u) * 8) = v;
        }
    }
}

// ---------------------------------------------------------------------------
// bf16 MFMA GEMM. OUT=0: fused QKV, N=3072, bf16 head-major outputs
// (Qh|Kh|Vh contiguous). OUT=2: N=1024, f32 row-major output.
// ---------------------------------------------------------------------------
template<int OUT>
__global__ __launch_bounds__(256) void gemm_bf16(
    const unsigned short* __restrict__ A, const unsigned short* __restrict__ Bt,
    const float* __restrict__ b0, const float* __restrict__ b1,
    const float* __restrict__ b2, void* __restrict__ Cout)
{
    __shared__ __align__(16) unsigned short As[2][128 * 64];
    __shared__ __align__(16) unsigned short Bs[2][128 * 64];

    const int tid = threadIdx.x;
    const int w  = tid >> 6;
    const int l  = tid & 63;
    const int g  = l >> 4, c = l & 15;
    const int wr = w >> 1, wc = w & 1;
    const int m0 = blockIdx.y * 128, n0 = blockIdx.x * 128;

    const int dr = l >> 3;
    const int gc = (l & 7) ^ dr;

    const unsigned short* aBase = A  + (size_t)(m0 + w * 32 + dr) * HH + gc * 8;
    const unsigned short* bBase = Bt + (size_t)(n0 + w * 32 + dr) * HH + gc * 8;

    f32x4 acc[4][4];
#pragma unroll
    for (int mi = 0; mi < 4; ++mi)
#pragma unroll
        for (int ni = 0; ni < 4; ++ni)
            acc[mi][ni] = (f32x4){0.f, 0.f, 0.f, 0.f};

    const int swz = (c & 7) * 8;

#define STAGE(kt_, bb) {                                                      \
    const int koff = (kt_) * 64;                                              \
    _Pragma("unroll")                                                         \
    for (int i_ = 0; i_ < 4; ++i_) {                                          \
        gl16(aBase + koff + (size_t)i_ * 8 * HH, (void*)&As[bb][(w*4+i_)*512]); \
        gl16(bBase + koff + (size_t)i_ * 8 * HH, (void*)&Bs[bb][(w*4+i_)*512]); \
    } }

    STAGE(0, 0);
    __syncthreads();
    int cur = 0;

    for (int kt = 0; kt < 16; ++kt) {
        if (kt < 15) STAGE(kt + 1, cur ^ 1);

        short8 af[2][4], bf[2][4];
#pragma unroll
        for (int ks = 0; ks < 2; ++ks) {
            const int kb = ks * 32;
#pragma unroll
            for (int mi = 0; mi < 4; ++mi) {
                const int row = wr * 64 + mi * 16 + c;
                af[ks][mi] = *(const short8*)&As[cur][row * 64 + ((kb + g * 8) ^ swz)];
            }
#pragma unroll
            for (int ni = 0; ni < 4; ++ni) {
                const int row = wc * 64 + ni * 16 + c;
                bf[ks][ni] = *(const short8*)&Bs[cur][row * 64 + ((kb + g * 8) ^ swz)];
            }
        }
#pragma unroll
        for (int ks = 0; ks < 2; ++ks)
#pragma unroll
            for (int mi = 0; mi < 4; ++mi)
#pragma unroll
                for (int ni = 0; ni < 4; ++ni)
                    acc[mi][ni] = __builtin_amdgcn_mfma_f32_16x16x32_bf16(
                        af[ks][mi], bf[ks][ni], acc[mi][ni], 0, 0, 0);

        __syncthreads();
        cur ^= 1;
    }
#undef STAGE

    // bias pointer select (block-uniform for OUT==0: 128 | 1024)
    const float* bp;
    int nbase;
    if (OUT == 0) {
        const int which = n0 >> 10;
        bp = which == 0 ? b0 : which == 1 ? b1 : b2;
        nbase = which << 10;
    } else { bp = b0; nbase = 0; }

#pragma unroll
    for (int ni = 0; ni < 4; ++ni) {
        const int n = n0 + wc * 64 + ni * 16 + c;
        const float bv = bp[n - nbase];
#pragma unroll
        for (int mi = 0; mi < 4; ++mi) {
            const int mBase = m0 + wr * 64 + mi * 16 + g * 4;
#pragma unroll
            for (int j = 0; j < 4; ++j) {
                const int m = mBase + j;
                const float val = acc[mi][ni][j] + bv;
                if (OUT == 0) {
                    const int which = n >> 10, nl = n & 1023;
                    const int b = m >> 11, si = m & 2047;
                    const int h = nl >> 6,  d = nl & 63;
                    ((unsigned short*)Cout)[(size_t)which * NTOK * HH +
                        (((size_t)(b * 16 + h)) * SS + si) * 64 + d] = f2b(val);
                } else {
                    ((float*)Cout)[(size_t)m * HH + n] = val;
                }
            }
        }
    }
}

// ---------------------------------------------------------------------------
// V head-major [bh][s][64] -> Vt [bh][64][s]
// ---------------------------------------------------------------------------
__global__ __launch_bounds__(256) void vtrans(
    const unsigned short* __restrict__ Vh, unsigned short* __restrict__ Vt)
{
    __shared__ unsigned short T[64][72];
    const int tid = threadIdx.x;
    const int bh = blockIdx.y;
    const int s0 = blockIdx.x * 64;
    {
        const int r = tid >> 2, dc = (tid & 3) * 16;
        const unsigned short* src = Vh + ((size_t)bh * SS + s0 + r) * 64 + dc;
        short8 v0 = *(const short8*)src;
        short8 v1 = *(const short8*)(src + 8);
#pragma unroll
        for (int j = 0; j < 8; ++j) {
            T[dc + j][r]     = (unsigned short)v0[j];
            T[dc + 8 + j][r] = (unsigned short)v1[j];
        }
    }
    __syncthreads();
    {
        const int d = tid >> 2, sc = (tid & 3) * 2;
#pragma unroll
        for (int u = 0; u < 2; ++u) {
            short8 v = *(const short8*)&T[d][(sc + u) * 8];
            *(short8*)(Vt + ((size_t)bh * 64 + d) * SS + s0 + (sc + u) * 8) = v;
        }
    }
}

// ---------------------------------------------------------------------------
// Flash attention, swapped-QK^T 32x32x16 MFMA, in-register softmax (T12),
// defer-max (T13). Block = 256 (4 waves x 32 q = 128 q). Grid (16, 32).
// ---------------------------------------------------------------------------
__global__ __launch_bounds__(256) void attn_mfma(
    const unsigned short* __restrict__ Qb, const unsigned short* __restrict__ Kb,
    const unsigned short* __restrict__ Vtb, const float* __restrict__ maskf,
    unsigned short* __restrict__ ctx)
{
    __shared__ __align__(16) unsigned short Ks[64 * 64];
    __shared__ __align__(16) unsigned short Vts[64 * 64];
    __shared__ __align__(16) float Sc[4][32];

    const int tid = threadIdx.x;
    const int l   = tid & 63;
    const int wq  = tid >> 6;       // wave 0..3
    const int hi  = l >> 5;         // 0/1
    const int c   = l & 31;         // q (softmax layout) / d or k col
    const int bh  = blockIdx.y;
    const int b   = bh >> 4, h = bh & 15;
    const int q0  = blockIdx.x * 128 + wq * 32;

    const unsigned short* Qp = Qb  + (size_t)bh * SS * 64;
    const unsigned short* Kp = Kb  + (size_t)bh * SS * 64;
    const unsigned short* Vp = Vtb + (size_t)bh * 64 * SS;
    const float* maskp = maskf + (size_t)b * SS;

    // Q B-fragments: qf[s] = Q[q0+c][s*16 + hi*8 .. +7]
    short8 qf[4];
    {
        const unsigned short* qrow = Qp + (size_t)(q0 + c) * 64 + hi * 8;
#pragma unroll
        for (int s = 0; s < 4; ++s) qf[s] = *(const short8*)(qrow + s * 16);
    }

    f32x16 oacc[2];
#pragma unroll
    for (int dt = 0; dt < 2; ++dt)
#pragma unroll
        for (int r = 0; r < 16; ++r) oacc[dt][r] = 0.f;

    float m_run = -1e30f, l_run = 0.f;

    const int r0 = tid >> 3, c0 = tid & 7;   // staging map

    for (int kt = 0; kt < 32; ++kt) {
        // ---- global loads ----
        const unsigned short* Kt = Kp + (size_t)(kt * 64) * 64;
        short8 kv0 = *(const short8*)(Kt + (size_t)r0 * 64 + c0 * 8);
        short8 kv1 = *(const short8*)(Kt + (size_t)(r0 + 32) * 64 + c0 * 8);
        short8 vv0 = *(const short8*)(Vp + (size_t)r0 * SS + kt * 64 + c0 * 8);
        short8 vv1 = *(const short8*)(Vp + (size_t)(r0 + 32) * SS + kt * 64 + c0 * 8);
        f32x4 mq[8];
#pragma unroll
        for (int t = 0; t < 8; ++t)
            mq[t] = *(const f32x4*)(maskp + kt * 64 + t * 8 + hi * 4);

        __syncthreads();
        *(short8*)((char*)Ks  + r0 * 128        + SWZ16(r0, c0 * 16)) = kv0;
        *(short8*)((char*)Ks  + (r0 + 32) * 128 + SWZ16(r0, c0 * 16)) = kv1;
        *(short8*)((char*)Vts + r0 * 128        + SWZ16(r0, c0 * 16)) = vv0;
        *(short8*)((char*)Vts + (r0 + 32) * 128 + SWZ16(r0, c0 * 16)) = vv1;
        __syncthreads();

        // ---- swapped QK^T: S^T[k][q], A=K B=Q ----
        f32x16 s4[2];
#pragma unroll
        for (int kt2 = 0; kt2 < 2; ++kt2) {
#pragma unroll
            for (int r = 0; r < 16; ++r) s4[kt2][r] = 0.f;
            const int row = kt2 * 32 + c;
#pragma unroll
            for (int s = 0; s < 4; ++s) {
                short8 kf = *(const short8*)((char*)Ks + row * 128 +
                                             SWZ16(row, (s * 2 + hi) * 16));
                s4[kt2] = __builtin_amdgcn_mfma_f32_32x32x16_bf16(kf, qf[s], s4[kt2], 0, 0, 0);
            }
        }

        // ---- scale + mask; per-lane max over 32 k ----
        float pv[32];
        float pmax = -1e30f;
#pragma unroll
        for (int kt2 = 0; kt2 < 2; ++kt2)
#pragma unroll
            for (int r = 0; r < 16; ++r) {
                const float sv = fmaf(mq[(r >> 2) + 4 * kt2][r & 3], -10000.f,
                                      s4[kt2][r] * 0.125f);
                pv[kt2 * 16 + r] = sv;
                pmax = fmaxf(pmax, sv);
            }
        pmax = fmaxf(pmax, __shfl_xor(pmax, 32, 64));

        // ---- defer-max rescale (T13) ----
        if (!__all(pmax <= m_run + 8.0f)) {
            const float mn = fmaxf(m_run, pmax);
            const float scold = __expf(m_run - mn);
            m_run = mn;
            l_run *= scold;
            Sc[wq][c] = scold;
            asm volatile("s_waitcnt lgkmcnt(0)" ::: "memory");
            f32x4 sq[4];
#pragma unroll
            for (int t = 0; t < 4; ++t)
                sq[t] = *(const f32x4*)&Sc[wq][t * 8 + hi * 4];
#pragma unroll
            for (int dt = 0; dt < 2; ++dt)
#pragma unroll
                for (int r = 0; r < 16; ++r)
                    oacc[dt][r] *= sq[r >> 2][r & 3];
        }

        // ---- exp + sum ----
        float tsum = 0.f;
#pragma unroll
        for (int j = 0; j < 32; ++j) {
            const float p = __expf(pv[j] - m_run);
            pv[j] = p;
            tsum += p;
        }
        tsum += __shfl_xor(tsum, 32, 64);
        l_run += tsum;

        // ---- P -> bf16 A-frags: cvt_pk + permlane32_swap (T12) ----
        unsigned wd[16];
#pragma unroll
        for (int j = 0; j < 16; ++j) wd[j] = pk2(pv[2 * j], pv[2 * j + 1]);
#pragma unroll
        for (int g4 = 0; g4 < 4; ++g4) {
            asm volatile("v_permlane32_swap_b32 %0, %1"
                         : "+v"(wd[4 * g4 + 0]), "+v"(wd[4 * g4 + 2]));
            asm volatile("v_permlane32_swap_b32 %0, %1"
                         : "+v"(wd[4 * g4 + 1]), "+v"(wd[4 * g4 + 3]));
        }

        // ---- PV: O[q][d] += P[q][k] V[k][d] ----
#pragma unroll
        for (int s = 0; s < 4; ++s) {
            union { unsigned u[4]; short8 s8; } pa;
#pragma unroll
            for (int u_ = 0; u_ < 4; ++u_) pa.u[u_] = wd[4 * s + u_];
#pragma unroll
            for (int dt = 0; dt < 2; ++dt) {
                const int vrow = dt * 32 + c;
                short8 vf = *(const short8*)((char*)Vts + vrow * 128 +
                                             SWZ16(vrow, (s * 2 + hi) * 16));
                oacc[dt] = __builtin_amdgcn_mfma_f32_32x32x16_bf16(pa.s8, vf, oacc[dt], 0, 0, 0);
            }
        }
    }

    // ---- epilogue: redistribute 1/l to O row layout, store bf16 ----
    Sc[wq][c] = l_run;
    asm volatile("s_waitcnt lgkmcnt(0)" ::: "memory");
    f32x4 lq[4];
#pragma unroll
    for (int t = 0; t < 4; ++t)
        lq[t] = *(const f32x4*)&Sc[wq][t * 8 + hi * 4];

#pragma unroll
    for (int dt = 0; dt < 2; ++dt)
#pragma unroll
        for (int r = 0; r < 16; ++r) {
            const int row = (r & 3) + 8 * (r >> 2) + 4 * hi;
            const float val = oacc[dt][r] / lq[r >> 2][r & 3];
            ctx[((size_t)(b * SS + q0 + row)) * HH + h * 64 + dt * 32 + c] = f2b(val);
        }
}

// ---------------------------------------------------------------------------
extern "C" void kernel_launch(void* const* d_in, const int* in_sizes, int n_in,
                              void* d_out, int out_size, void* d_ws, size_t ws_size,
                              hipStream_t stream)
{
    const float* hs   = (const float*)d_in[0];
    const float* mask = (const float*)d_in[1];
    const float* Wq   = (const float*)d_in[2];
    const float* bq   = (const float*)d_in[3];
    const float* Wk   = (const float*)d_in[4];
    const float* bk   = (const float*)d_in[5];
    const float* Wv   = (const float*)d_in[6];
    const float* bv   = (const float*)d_in[7];
    const float* Wo   = (const float*)d_in[8];
    const float* bo   = (const float*)d_in[9];
    float* out = (float*)d_out;

    unsigned short* Ab   = (unsigned short*)d_ws;
    unsigned short* Wt   = Ab + (size_t)NTOK * HH;
    unsigned short* Qh   = Wt + (size_t)4 * HH * HH;   // Qh|Kh|Vh contiguous
    unsigned short* Kh   = Qh + (size_t)NTOK * HH;
    unsigned short* Vh   = Kh + (size_t)NTOK * HH;
    unsigned short* Vt   = Vh + (size_t)NTOK * HH;
    unsigned short* ctxb = Vt + (size_t)NTOK * HH;

    dim3 blk(256);

    cvt_hs<<<dim3(NTOK * HH / (8 * 256)), blk, 0, stream>>>(hs, Ab);
    transpose_w<<<dim3(16, 16, 4), blk, 0, stream>>>(Wq, Wk, Wv, Wo, Wt);

    // fused QKV GEMM: N = 3072
    gemm_bf16<0><<<dim3(24, 32), blk, 0, stream>>>(Ab, Wt, bq, bk, bv, Qh);

    vtrans<<<dim3(SS / 64, NB * NHEAD), blk, 0, stream>>>(Vh, Vt);

    attn_mfma<<<dim3(SS / 128, NB * NHEAD), blk, 0, stream>>>(Qh, Kh, Vt, mask, ctxb);

    gemm_bf16<2><<<dim3(8, 32), blk, 0, stream>>>(ctxb, Wt + 3 * (size_t)HH * HH,
                                                  bo, bo, bo, out);
}